// Round 5
// baseline (300.793 us; speedup 1.0000x reference)
//
#include <hip/hip_runtime.h>
#include <math.h>

// Problem constants (from setup_inputs)
constexpr int B = 8, N = 65536, C = 80, M = 64;
constexpr int APB = 256;          // anchors per block (64 per wave)
constexpr int BPI = N / APB;      // 256 blocks per image
constexpr int NBLK = B * BPI;     // 2048 blocks total
constexpr int K4 = C / 4;         // 20 float4 per anchor
constexpr float F_ALPHA = 0.25f;
constexpr float F_EPS = 1e-4f;
constexpr float F_BETA = 1.0f / 9.0f;

__device__ __forceinline__ float waveReduceSum(float v) {
    #pragma unroll
    for (int off = 32; off > 0; off >>= 1) v += __shfl_down(v, off, 64);
    return v;
}

// One block = 256 anchors (4 waves x 64). Per wave: issue the 20 coalesced
// float4 loads of its own 64x80 cls chunk FIRST, run the IoU assignment while
// they're in flight, then the focal sweep consuming registers (codes via
// __shfl from the owning lane). Block writes one float4 partial, then the
// LAST block (ticket == NBLK-1) reduces all partials and writes the scalar —
// no second kernel dispatch.
__global__ __launch_bounds__(256) void fused_kernel(
    const float* __restrict__ anchors,   // [N,4]
    const float* __restrict__ regs,      // [B,N,4]
    const float* __restrict__ ann,       // [B,M,5]
    const float* __restrict__ cls,       // [B,N,C]
    float4* __restrict__ partials,       // [NBLK]
    unsigned int* __restrict__ counter,  // zeroed by memset node each replay
    float* __restrict__ out)
{
    const int b = blockIdx.y;
    const int n0 = blockIdx.x * APB;
    const int tid = threadIdx.x;
    const int wave = tid >> 6, lane = tid & 63;
    const int n = n0 + tid;              // this thread's anchor

    __shared__ float4 sbox[M];           // x1,y1,x2,y2
    __shared__ float2 sal[M];            // area, label
    __shared__ float  swsum[3][4];

    if (tid < M) {
        const float* a = ann + (size_t)(b * M + tid) * 5;
        const float x1 = a[0], y1 = a[1], x2 = a[2], y2 = a[3], lb = a[4];
        sbox[tid] = make_float4(x1, y1, x2, y2);
        sal[tid] = make_float2((x2 - x1) * (y2 - y1), lb);
    }
    __syncthreads();

    // ---- issue the wave's 20 coalesced cls loads (1 KB per instruction) ----
    const float4* __restrict__ cpw =
        reinterpret_cast<const float4*>(cls) + ((size_t)b * N + n0 + wave * 64) * K4;
    float4 v[K4];
    #pragma unroll
    for (int k = 0; k < K4; ++k) v[k] = cpw[k * 64 + lane];

    // ---- IoU assignment for own anchor (overlaps the loads above) ----------
    const float4 av = reinterpret_cast<const float4*>(anchors)[n];
    const float aarea = (av.z - av.x) * (av.w - av.y);
    float best = -2.0f;
    int bestj = 0;
    #pragma unroll 8
    for (int j = 0; j < M; ++j) {
        const float4 bb = sbox[j];
        const float2 al = sal[j];
        const float iw = fmaxf(fminf(av.z, bb.z) - fmaxf(av.x, bb.x), 0.0f);
        const float ih = fmaxf(fminf(av.w, bb.w) - fmaxf(av.y, bb.y), 0.0f);
        const float inter = iw * ih;
        const float ua = fmaxf(aarea + al.x - inter, 1e-8f);
        float iou = __fdividef(inter, ua);
        iou = (al.y != -1.0f) ? iou : -1.0f;       // invalid GT -> -1
        if (iou > best) { best = iou; bestj = j; } // strict > == argmax first-occ
    }
    const bool pos = best > 0.5f;
    const bool neg = best < 0.4f;
    const int code = pos ? (int)sal[bestj].y : (neg ? -2 : -1);

    float np = 0.0f, rl = 0.0f;
    if (pos) {
        np = 1.0f;
        const float4 g = sbox[bestj];
        float gw = g.z - g.x, gh = g.w - g.y;
        const float gcx = g.x + 0.5f * gw, gcy = g.y + 0.5f * gh;
        gw = fmaxf(gw, 1.0f);
        gh = fmaxf(gh, 1.0f);
        const float aw = av.z - av.x, ah = av.w - av.y;
        const float acx = av.x + 0.5f * aw, acy = av.y + 0.5f * ah;
        const float t0 = ((gcx - acx) / aw) / 0.1f;
        const float t1 = ((gcy - acy) / ah) / 0.1f;
        const float t2 = logf(gw / aw) / 0.2f;
        const float t3 = logf(gh / ah) / 0.2f;
        const float4 rv = reinterpret_cast<const float4*>(regs)[(size_t)b * N + n];
        const float d0 = fabsf(t0 - rv.x), d1 = fabsf(t1 - rv.y);
        const float d2 = fabsf(t2 - rv.z), d3 = fabsf(t3 - rv.w);
        auto sl1 = [](float d) { return d < F_BETA ? 4.5f * d * d : d - (0.5f / 9.0f); };
        rl = sl1(d0) + sl1(d1) + sl1(d2) + sl1(d3);
    }

    // ---- focal sweep: consume the 20 registers, codes via shuffle ----------
    float a0 = 0.0f, a1 = 0.0f, a2 = 0.0f, a3 = 0.0f;
    #pragma unroll
    for (int k = 0; k < K4; ++k) {
        const int f = k * 64 + lane;
        const int nl = f / 20;                     // owning lane (0..63)
        const int c0 = (f - nl * 20) * 4;
        const int cd = __shfl(code, nl, 64);
        const bool ign = (cd == -1);
        const float aneg = ign ? 0.0f : (1.0f - F_ALPHA);
        const float apos = ign ? 0.0f : F_ALPHA;
        const float vv[4] = {v[k].x, v[k].y, v[k].z, v[k].w};
        float* accp[4] = {&a0, &a1, &a2, &a3};
        #pragma unroll
        for (int q = 0; q < 4; ++q) {
            const float x = fminf(fmaxf(vv[q], F_EPS), 1.0f - F_EPS);
            const float one = 1.0f - x;
            const bool p = (cd == c0 + q);
            const float fw = p ? one : x;
            const float y = p ? x : one;
            const float a = p ? apos : aneg;
            *accp[q] = fmaf(a * fw * fw, -__logf(y), *accp[q]);
        }
    }

    // ---- block reduce, one partial per block --------------------------------
    np = waveReduceSum(np);
    rl = waveReduceSum(rl);
    float cl = waveReduceSum((a0 + a1) + (a2 + a3));
    if (lane == 0) { swsum[0][wave] = np; swsum[1][wave] = rl; swsum[2][wave] = cl; }
    __syncthreads();
    if (tid == 0) {
        float4 r;
        r.x = swsum[0][0] + swsum[0][1] + swsum[0][2] + swsum[0][3];
        r.y = swsum[1][0] + swsum[1][1] + swsum[1][2] + swsum[1][3];
        r.z = swsum[2][0] + swsum[2][1] + swsum[2][2] + swsum[2][3];
        r.w = 0.0f;
        partials[b * BPI + blockIdx.x] = r;
    }

    // ---- last-block final reduction (deterministic fixed-order sum) ---------
    __threadfence();                               // release: partial visible
    __shared__ unsigned int sticket;
    if (tid == 0) sticket = atomicAdd(counter, 1u);
    __syncthreads();
    if (sticket == (unsigned)(NBLK - 1)) {
        __threadfence();                           // acquire side
        const int b2 = tid >> 5, sl = tid & 31;    // 32 lanes per image
        float snp = 0.0f, srl = 0.0f, scl = 0.0f;
        #pragma unroll
        for (int k = 0; k < BPI / 32; ++k) {
            const float4 p = partials[b2 * BPI + sl + k * 32];
            snp += p.x; srl += p.y; scl += p.z;
        }
        #pragma unroll
        for (int off = 16; off > 0; off >>= 1) {   // tree within 32-lane group
            snp += __shfl_down(snp, off, 64);
            srl += __shfl_down(srl, off, 64);
            scl += __shfl_down(scl, off, 64);
        }
        __shared__ float simg[8];
        if (sl == 0) {
            const float c = scl / fmaxf(snp, 1.0f);
            const float r = (snp > 0.0f) ? srl / (fmaxf(snp, 1.0f) * 4.0f) : 0.0f;
            simg[b2] = c + r;
        }
        __syncthreads();
        if (tid == 0) {
            float tot = 0.0f;
            #pragma unroll
            for (int i = 0; i < B; ++i) tot += simg[i];
            out[0] = tot * (1.0f / (float)B);
        }
    }
}

extern "C" void kernel_launch(void* const* d_in, const int* in_sizes, int n_in,
                              void* d_out, int out_size, void* d_ws, size_t ws_size,
                              hipStream_t stream) {
    const float* classifications = (const float*)d_in[0]; // [B,N,C]
    const float* regressions     = (const float*)d_in[1]; // [B,N,4]
    const float* anchors         = (const float*)d_in[2]; // [1,N,4]
    const float* annotations     = (const float*)d_in[3]; // [B,M,5]
    float* out = (float*)d_out;

    float4* partials = (float4*)d_ws;                     // NBLK float4 = 32 KiB
    unsigned int* counter = (unsigned int*)((char*)d_ws + (size_t)NBLK * 16);

    hipMemsetAsync(counter, 0, 4, stream);                // ticket = 0 each replay

    dim3 g(BPI, B);
    fused_kernel<<<g, 256, 0, stream>>>(anchors, regressions, annotations,
                                        classifications, partials, counter, out);
}

// Round 6
// 83.424 us; speedup vs baseline: 3.6056x; 3.6056x over previous
//
#include <hip/hip_runtime.h>
#include <math.h>

// Problem constants (from setup_inputs)
constexpr int B = 8, N = 65536, C = 80, M = 64;
constexpr int APB = 256;          // anchors per block
constexpr int BPI = N / APB;      // 256 blocks per image
constexpr int NBLK = B * BPI;     // 2048 blocks total
constexpr float F_ALPHA = 0.25f;
constexpr float F_EPS = 1e-4f;
constexpr float F_BETA = 1.0f / 9.0f;

__device__ __forceinline__ float waveReduceSum(float v) {
    #pragma unroll
    for (int off = 32; off > 0; off >>= 1) v += __shfl_down(v, off, 64);
    return v;
}

// One block = 256 anchors of one image (round-2 structure: LDS codes, direct
// loads in the sweep -> low VGPR, no spill). Block results go to 24 global
// accumulators via device-scope atomicAdd; thread 0 then waits vmcnt(0),
// takes a ticket, and the last block computes the scalar from coherent
// atomic loads. No device fences, no second dispatch.
__global__ __launch_bounds__(256) void fused_kernel(
    const float* __restrict__ anchors,   // [N,4]
    const float* __restrict__ regs,      // [B,N,4]
    const float* __restrict__ ann,       // [B,M,5]
    const float* __restrict__ cls,       // [B,N,C]
    float* __restrict__ accum,           // [24]: np[8], rl[8], cl[8] (zeroed/replay)
    unsigned int* __restrict__ counter,  // zeroed each replay
    float* __restrict__ out)
{
    const int b = blockIdx.y;
    const int n0 = blockIdx.x * APB;
    const int tid = threadIdx.x;
    const int wave = tid >> 6, lane = tid & 63;

    __shared__ float4 sbox[M];      // x1,y1,x2,y2
    __shared__ float2 sal[M];       // area, label
    __shared__ int    scode[APB];   // pos->class, neg->-2, ignore->-1
    __shared__ float  swsum[3][4];

    if (tid < M) {
        const float* a = ann + (size_t)(b * M + tid) * 5;
        const float x1 = a[0], y1 = a[1], x2 = a[2], y2 = a[3], lb = a[4];
        sbox[tid] = make_float4(x1, y1, x2, y2);
        sal[tid] = make_float2((x2 - x1) * (y2 - y1), lb);
    }
    __syncthreads();

    // ---------------- phase 1: assignment ----------------
    const int n = n0 + tid;
    const float4 av = reinterpret_cast<const float4*>(anchors)[n];
    const float aarea = (av.z - av.x) * (av.w - av.y);

    float best = -2.0f;
    int bestj = 0;
    #pragma unroll 8
    for (int j = 0; j < M; ++j) {
        const float4 bb = sbox[j];
        const float2 al = sal[j];
        const float iw = fmaxf(fminf(av.z, bb.z) - fmaxf(av.x, bb.x), 0.0f);
        const float ih = fmaxf(fminf(av.w, bb.w) - fmaxf(av.y, bb.y), 0.0f);
        const float inter = iw * ih;
        const float ua = fmaxf(aarea + al.x - inter, 1e-8f);
        float iou = __fdividef(inter, ua);
        iou = (al.y != -1.0f) ? iou : -1.0f;       // invalid GT -> -1
        if (iou > best) { best = iou; bestj = j; } // strict > == argmax first-occ
    }
    const bool pos = best > 0.5f;
    const bool neg = best < 0.4f;
    const int code = pos ? (int)sal[bestj].y : (neg ? -2 : -1);
    scode[tid] = code;

    float np = 0.0f, rl = 0.0f;
    if (pos) {
        np = 1.0f;
        const float4 g = sbox[bestj];
        float gw = g.z - g.x, gh = g.w - g.y;
        const float gcx = g.x + 0.5f * gw, gcy = g.y + 0.5f * gh;
        gw = fmaxf(gw, 1.0f);
        gh = fmaxf(gh, 1.0f);
        const float aw = av.z - av.x, ah = av.w - av.y;
        const float acx = av.x + 0.5f * aw, acy = av.y + 0.5f * ah;
        const float t0 = ((gcx - acx) / aw) / 0.1f;
        const float t1 = ((gcy - acy) / ah) / 0.1f;
        const float t2 = logf(gw / aw) / 0.2f;
        const float t3 = logf(gh / ah) / 0.2f;
        const float4 rv = reinterpret_cast<const float4*>(regs)[(size_t)b * N + n];
        const float d0 = fabsf(t0 - rv.x), d1 = fabsf(t1 - rv.y);
        const float d2 = fabsf(t2 - rv.z), d3 = fabsf(t3 - rv.w);
        auto sl1 = [](float d) { return d < F_BETA ? 4.5f * d * d : d - (0.5f / 9.0f); };
        rl = sl1(d0) + sl1(d1) + sl1(d2) + sl1(d3);
    }

    np = waveReduceSum(np);
    rl = waveReduceSum(rl);
    if (lane == 0) { swsum[0][wave] = np; swsum[1][wave] = rl; }
    __syncthreads(); // publishes scode + swsum

    // ---------------- phase 2: focal cls loss (direct loads, branchless) -----
    const float4* __restrict__ cp =
        reinterpret_cast<const float4*>(cls) + ((size_t)b * N + n0) * (C / 4);
    float a0 = 0.0f, a1 = 0.0f, a2 = 0.0f, a3 = 0.0f;
    #pragma unroll 4
    for (int k = 0; k < APB * C / 4 / 256; ++k) {   // 20 iterations
        const int f = k * 256 + tid;
        const int nl = f / 20;                      // magic-mul div
        const int c0 = (f - nl * 20) * 4;
        const int code2 = scode[nl];
        const bool ign = (code2 == -1);
        const float aneg = ign ? 0.0f : (1.0f - F_ALPHA);
        const float apos = ign ? 0.0f : F_ALPHA;
        const float4 v = cp[f];                     // always load (branchless)
        const float vv[4] = {v.x, v.y, v.z, v.w};
        float* accp[4] = {&a0, &a1, &a2, &a3};
        #pragma unroll
        for (int q = 0; q < 4; ++q) {
            const float x = fminf(fmaxf(vv[q], F_EPS), 1.0f - F_EPS);
            const float one = 1.0f - x;
            const bool p = (code2 == c0 + q);
            const float fw = p ? one : x;
            const float y = p ? x : one;
            const float a = p ? apos : aneg;
            *accp[q] = fmaf(a * fw * fw, -__logf(y), *accp[q]);
        }
    }
    float cl = waveReduceSum((a0 + a1) + (a2 + a3));
    if (lane == 0) swsum[2][wave] = cl;
    __syncthreads();

    // ---------------- block results -> global accumulators -------------------
    if (tid == 0) {
        const float bnp = swsum[0][0] + swsum[0][1] + swsum[0][2] + swsum[0][3];
        const float brl = swsum[1][0] + swsum[1][1] + swsum[1][2] + swsum[1][3];
        const float bcl = swsum[2][0] + swsum[2][1] + swsum[2][2] + swsum[2][3];
        atomicAdd(&accum[b], bnp);          // device-scope, coherence-point ops
        atomicAdd(&accum[8 + b], brl);
        atomicAdd(&accum[16 + b], bcl);

        // Guarantee this block's adds are globally performed before the ticket.
        asm volatile("s_waitcnt vmcnt(0)" ::: "memory");
        const unsigned int t = atomicAdd(counter, 1u);
        if (t == (unsigned)(NBLK - 1)) {
            // All 2047 other blocks' adds completed before their tickets;
            // read via coherent agent-scope loads (no cache-fence needed).
            float tot = 0.0f;
            #pragma unroll
            for (int i = 0; i < B; ++i) {
                const float inp = __hip_atomic_load(&accum[i],      __ATOMIC_RELAXED, __HIP_MEMORY_SCOPE_AGENT);
                const float irl = __hip_atomic_load(&accum[8 + i],  __ATOMIC_RELAXED, __HIP_MEMORY_SCOPE_AGENT);
                const float icl = __hip_atomic_load(&accum[16 + i], __ATOMIC_RELAXED, __HIP_MEMORY_SCOPE_AGENT);
                const float c = icl / fmaxf(inp, 1.0f);
                const float r = (inp > 0.0f) ? irl / (fmaxf(inp, 1.0f) * 4.0f) : 0.0f;
                tot += c + r;
            }
            out[0] = tot * (1.0f / (float)B);
        }
    }
}

extern "C" void kernel_launch(void* const* d_in, const int* in_sizes, int n_in,
                              void* d_out, int out_size, void* d_ws, size_t ws_size,
                              hipStream_t stream) {
    const float* classifications = (const float*)d_in[0]; // [B,N,C]
    const float* regressions     = (const float*)d_in[1]; // [B,N,4]
    const float* anchors         = (const float*)d_in[2]; // [1,N,4]
    const float* annotations     = (const float*)d_in[3]; // [B,M,5]
    float* out = (float*)d_out;

    float* accum = (float*)d_ws;                           // 24 floats
    unsigned int* counter = (unsigned int*)((char*)d_ws + 24 * sizeof(float));

    hipMemsetAsync(d_ws, 0, 24 * sizeof(float) + sizeof(unsigned int), stream);

    dim3 g(BPI, B);
    fused_kernel<<<g, 256, 0, stream>>>(anchors, regressions, annotations,
                                        classifications, accum, counter, out);
}

// Round 7
// 39.143 us; speedup vs baseline: 7.6844x; 2.1312x over previous
//
#include <hip/hip_runtime.h>
#include <math.h>

// Problem constants (from setup_inputs)
constexpr int B = 8, N = 65536, C = 80, M = 64;
constexpr int APB = 256;          // anchors per block
constexpr int BPI = N / APB;      // 256 blocks per image
constexpr float F_ALPHA = 0.25f;
constexpr float F_EPS = 1e-4f;
constexpr float F_BETA = 1.0f / 9.0f;
constexpr float K_NEG = 0.75f * 0.6931471805599453f;  // (1-alpha)*ln2

__device__ __forceinline__ float waveReduceSum(float v) {
    #pragma unroll
    for (int off = 32; off > 0; off >>= 1) v += __shfl_down(v, off, 64);
    return v;
}

// One block = 256 anchors of one image.
// Phase 1: division-free IoU argmax (cross-multiplied comparisons) + reg loss.
// Phase 2: focal cls sweep with hoisted alpha: accumulate x^2*log2(1-x) only;
//          positive-class elements corrected via a rare per-anchor delta term.
// Block writes one float4 partial; tiny final kernel reduces.
__global__ __launch_bounds__(256) void fused_kernel(
    const float* __restrict__ anchors,   // [N,4]
    const float* __restrict__ regs,      // [B,N,4]
    const float* __restrict__ ann,       // [B,M,5]
    const float* __restrict__ cls,       // [B,N,C]
    float4* __restrict__ partials)       // [B*BPI]
{
    const int b = blockIdx.y;
    const int n0 = blockIdx.x * APB;
    const int tid = threadIdx.x;
    const int wave = tid >> 6, lane = tid & 63;

    __shared__ float4 sbox[M];      // x1,y1,x2,y2
    __shared__ float2 sal[M];       // area, label
    __shared__ int    scode[APB];   // pos->class, neg->-2, ignore->-1
    __shared__ float  swsum[3][4];

    if (tid < M) {
        const float* a = ann + (size_t)(b * M + tid) * 5;
        const float x1 = a[0], y1 = a[1], x2 = a[2], y2 = a[3], lb = a[4];
        sbox[tid] = make_float4(x1, y1, x2, y2);
        sal[tid] = make_float2((x2 - x1) * (y2 - y1), lb);
    }
    __syncthreads();

    // ---------------- phase 1: division-free assignment ----------------
    const int n = n0 + tid;
    const float4 av = reinterpret_cast<const float4*>(anchors)[n];
    const float aarea = (av.z - av.x) * (av.w - av.y);

    // best IoU kept as ratio bn/bd (bd >= 0); init (-1, 0) == -inf sentinel
    // that loses to every candidate, incl. masked ones (ratio -1).
    float bn = -1.0f, bd = 0.0f;
    int bestj = 0;
    #pragma unroll 8
    for (int j = 0; j < M; ++j) {
        const float4 bb = sbox[j];
        const float2 al = sal[j];
        const float iw = fmaxf(fminf(av.z, bb.z) - fmaxf(av.x, bb.x), 0.0f);
        const float ih = fmaxf(fminf(av.w, bb.w) - fmaxf(av.y, bb.y), 0.0f);
        const float inter = iw * ih;
        const float ua = fmaxf(aarea + al.x - inter, 1e-8f);
        const float cn = (al.y != -1.0f) ? inter : -ua;   // masked -> ratio -1
        // cn/ua > bn/bd  <=>  cn*bd > bn*ua  (both dens >= 0)
        const bool take = cn * bd > bn * ua;              // strict > == first-occ
        bn = take ? cn : bn;
        bd = take ? ua : bd;
        bestj = take ? j : bestj;
    }
    const bool pos = bn > 0.5f * bd;
    const bool neg = bn < 0.4f * bd;
    const int code = pos ? (int)sal[bestj].y : (neg ? -2 : -1);
    scode[tid] = code;

    float np = 0.0f, rl = 0.0f, delta = 0.0f;
    if (pos) {
        np = 1.0f;
        const float4 g = sbox[bestj];
        float gw = g.z - g.x, gh = g.w - g.y;
        const float gcx = g.x + 0.5f * gw, gcy = g.y + 0.5f * gh;
        gw = fmaxf(gw, 1.0f);
        gh = fmaxf(gh, 1.0f);
        const float aw = av.z - av.x, ah = av.w - av.y;
        const float acx = av.x + 0.5f * aw, acy = av.y + 0.5f * ah;
        const float t0 = ((gcx - acx) / aw) / 0.1f;
        const float t1 = ((gcy - acy) / ah) / 0.1f;
        const float t2 = logf(gw / aw) / 0.2f;
        const float t3 = logf(gh / ah) / 0.2f;
        const float4 rv = reinterpret_cast<const float4*>(regs)[(size_t)b * N + n];
        const float d0 = fabsf(t0 - rv.x), d1 = fabsf(t1 - rv.y);
        const float d2 = fabsf(t2 - rv.z), d3 = fabsf(t3 - rv.w);
        auto sl1 = [](float d) { return d < F_BETA ? 4.5f * d * d : d - (0.5f / 9.0f); };
        rl = sl1(d0) + sl1(d1) + sl1(d2) + sl1(d3);

        // Positive-class correction for the sweep (which applies the negative
        // formula to every non-ignored element): subtract the neg-term the
        // sweep will add for (n, code) and add the true positive term.
        const float xp = cls[((size_t)b * N + n) * C + code];
        const float x = fminf(fmaxf(xp, F_EPS), 1.0f - F_EPS);  // same clamp as sweep
        const float om = 1.0f - x;
        delta = F_ALPHA * om * om * (-__logf(x))
              - (1.0f - F_ALPHA) * x * x * (-__logf(om));
    }

    np = waveReduceSum(np);
    rl = waveReduceSum(rl);
    if (lane == 0) { swsum[0][wave] = np; swsum[1][wave] = rl; }
    __syncthreads(); // publishes scode + swsum

    // ---------------- phase 2: negative-formula sweep (hoisted alpha) --------
    // acc accumulates x^2 * log2(1-x)  (<= 0); scaled once by -K_NEG at the end.
    const float4* __restrict__ cp =
        reinterpret_cast<const float4*>(cls) + ((size_t)b * N + n0) * (C / 4);
    float a0 = 0.0f, a1 = 0.0f, a2 = 0.0f, a3 = 0.0f;
    #pragma unroll 4
    for (int k = 0; k < APB * C / 4 / 256; ++k) {   // 20 iterations
        const int f = k * 256 + tid;
        const int nl = f / 20;                      // magic-mul div
        const int code2 = scode[nl];
        const float m = (code2 == -1) ? 0.0f : 1.0f; // ignore -> zero the term
        const float4 v = cp[f];
        const float vv[4] = {v.x, v.y, v.z, v.w};
        float* accp[4] = {&a0, &a1, &a2, &a3};
        #pragma unroll
        for (int q = 0; q < 4; ++q) {
            const float x = fminf(fmaxf(vv[q], F_EPS), 1.0f - F_EPS) * m;
            *accp[q] = fmaf(x * x, __log2f(1.0f - x), *accp[q]);
        }
    }
    const float cl_t = fmaf(-K_NEG, (a0 + a1) + (a2 + a3), delta);
    float cl = waveReduceSum(cl_t);
    if (lane == 0) swsum[2][wave] = cl;
    __syncthreads();

    if (tid == 0) {
        float4 r;
        r.x = swsum[0][0] + swsum[0][1] + swsum[0][2] + swsum[0][3];
        r.y = swsum[1][0] + swsum[1][1] + swsum[1][2] + swsum[1][3];
        r.z = swsum[2][0] + swsum[2][1] + swsum[2][2] + swsum[2][3];
        r.w = 0.0f;
        partials[b * BPI + blockIdx.x] = r;
    }
}

// One wave per image reduces its 256 block-partials, then thread 0 means.
__global__ __launch_bounds__(512) void final_kernel(
    const float4* __restrict__ partials, float* __restrict__ out)
{
    const int wave = threadIdx.x >> 6, lane = threadIdx.x & 63;
    __shared__ float simg[8];

    float np = 0.0f, rl = 0.0f, cl = 0.0f;
    for (int k = lane; k < BPI; k += 64) {
        const float4 p = partials[wave * BPI + k];
        np += p.x; rl += p.y; cl += p.z;
    }
    np = waveReduceSum(np);
    rl = waveReduceSum(rl);
    cl = waveReduceSum(cl);
    if (lane == 0) {
        const float c = cl / fmaxf(np, 1.0f);
        const float r = (np > 0.0f) ? rl / (fmaxf(np, 1.0f) * 4.0f) : 0.0f;
        simg[wave] = c + r;
    }
    __syncthreads();
    if (threadIdx.x == 0) {
        float t = 0.0f;
        #pragma unroll
        for (int b2 = 0; b2 < B; ++b2) t += simg[b2];
        out[0] = t * (1.0f / (float)B);
    }
}

extern "C" void kernel_launch(void* const* d_in, const int* in_sizes, int n_in,
                              void* d_out, int out_size, void* d_ws, size_t ws_size,
                              hipStream_t stream) {
    const float* classifications = (const float*)d_in[0]; // [B,N,C]
    const float* regressions     = (const float*)d_in[1]; // [B,N,4]
    const float* anchors         = (const float*)d_in[2]; // [1,N,4]
    const float* annotations     = (const float*)d_in[3]; // [B,M,5]
    float* out = (float*)d_out;
    float4* partials = (float4*)d_ws;                     // B*BPI = 2048 float4

    dim3 g(BPI, B);
    fused_kernel<<<g, 256, 0, stream>>>(anchors, regressions, annotations,
                                        classifications, partials);
    final_kernel<<<1, 512, 0, stream>>>(partials, out);
}

// Round 8
// 37.583 us; speedup vs baseline: 8.0033x; 1.0415x over previous
//
#include <hip/hip_runtime.h>
#include <math.h>

// Problem constants (from setup_inputs)
constexpr int B = 8, N = 65536, C = 80, M = 64;
constexpr int APB = 256;          // anchors per block
constexpr int BPI = N / APB;      // 256 blocks per image
constexpr float F_ALPHA = 0.25f;
constexpr float F_EPS = 1e-4f;
constexpr float F_BETA = 1.0f / 9.0f;
constexpr float K_NEG = 0.75f * 0.6931471805599453f;  // (1-alpha)*ln2

__device__ __forceinline__ float waveReduceSum(float v) {
    #pragma unroll
    for (int off = 32; off > 0; off >>= 1) v += __shfl_down(v, off, 64);
    return v;
}

// One block = 256 anchors of one image.
// Phase 1: division-free IoU argmax; invalid GTs folded in as area=+inf
//          (ua=inf auto-loses every cross-multiplied comparison and forces
//          pos=false if it wins by default) -> no per-iter validity select.
// Phase 2: negative-formula focal sweep with per-anchor LIMIT fusion:
//          x = fmin(v, lim), lim = 0 for ignored anchors (term -> 0) else
//          1-eps (upper clamp). 6 VALU slots/element.
//          Positive-class elements corrected by a rare per-anchor delta.
__global__ __launch_bounds__(256) void fused_kernel(
    const float* __restrict__ anchors,   // [N,4]
    const float* __restrict__ regs,      // [B,N,4]
    const float* __restrict__ ann,       // [B,M,5]
    const float* __restrict__ cls,       // [B,N,C]
    float4* __restrict__ partials)       // [B*BPI]
{
    const int b = blockIdx.y;
    const int n0 = blockIdx.x * APB;
    const int tid = threadIdx.x;
    const int wave = tid >> 6, lane = tid & 63;

    __shared__ float4 sbox[M];      // x1,y1,x2,y2
    __shared__ float  sarea[M];     // area, or +inf for invalid GT
    __shared__ float  slab[M];      // label
    __shared__ float  slim[APB];    // sweep limit: 0 (ignore) or 1-eps
    __shared__ float  swsum[3][4];

    if (tid < M) {
        const float* a = ann + (size_t)(b * M + tid) * 5;
        const float x1 = a[0], y1 = a[1], x2 = a[2], y2 = a[3], lb = a[4];
        sbox[tid] = make_float4(x1, y1, x2, y2);
        sarea[tid] = (lb != -1.0f) ? (x2 - x1) * (y2 - y1) : __builtin_huge_valf();
        slab[tid] = lb;
    }
    __syncthreads();

    // ---------------- phase 1: division-free assignment ----------------
    const int n = n0 + tid;
    const float4 av = reinterpret_cast<const float4*>(anchors)[n];
    const float aarea = (av.z - av.x) * (av.w - av.y);

    // best IoU as ratio bn/bd; init (-1, 0) sentinel loses to everything.
    float bn = -1.0f, bd = 0.0f;
    int bestj = 0;
    #pragma unroll 8
    for (int j = 0; j < M; ++j) {
        const float4 bb = sbox[j];
        const float iw = fmaxf(fminf(av.z, bb.z) - fmaxf(av.x, bb.x), 0.0f);
        const float ih = fmaxf(fminf(av.w, bb.w) - fmaxf(av.y, bb.y), 0.0f);
        const float inter = iw * ih;
        const float ua = fmaxf(aarea + sarea[j] - inter, 1e-8f); // inf if invalid
        // inter/ua > bn/bd  <=>  inter*bd > bn*ua  (dens >= 0; inf auto-loses:
        // bn*inf = inf beats any finite lhs; NaN (0*inf) compares false = keep)
        const bool take = inter * bd > bn * ua;
        bn = take ? inter : bn;
        bd = take ? ua : bd;
        bestj = take ? j : bestj;
    }
    const bool pos = bn > 0.5f * bd;   // bd=inf -> false
    const bool neg = bn < 0.4f * bd;   // bd=inf -> true (matches ref: max valid iou 0)
    const int code = pos ? (int)slab[bestj] : (neg ? -2 : -1);
    slim[tid] = (pos || neg) ? (1.0f - F_EPS) : 0.0f;   // ignore -> 0

    float np = 0.0f, rl = 0.0f, delta = 0.0f;
    if (pos) {
        np = 1.0f;
        const float4 g = sbox[bestj];
        float gw = g.z - g.x, gh = g.w - g.y;
        const float gcx = g.x + 0.5f * gw, gcy = g.y + 0.5f * gh;
        gw = fmaxf(gw, 1.0f);
        gh = fmaxf(gh, 1.0f);
        const float aw = av.z - av.x, ah = av.w - av.y;
        const float acx = av.x + 0.5f * aw, acy = av.y + 0.5f * ah;
        const float t0 = ((gcx - acx) / aw) / 0.1f;
        const float t1 = ((gcy - acy) / ah) / 0.1f;
        const float t2 = logf(gw / aw) / 0.2f;
        const float t3 = logf(gh / ah) / 0.2f;
        const float4 rv = reinterpret_cast<const float4*>(regs)[(size_t)b * N + n];
        const float d0 = fabsf(t0 - rv.x), d1 = fabsf(t1 - rv.y);
        const float d2 = fabsf(t2 - rv.z), d3 = fabsf(t3 - rv.w);
        auto sl1 = [](float d) { return d < F_BETA ? 4.5f * d * d : d - (0.5f / 9.0f); };
        rl = sl1(d0) + sl1(d1) + sl1(d2) + sl1(d3);

        // Correction: remove the negative-formula term the sweep adds for the
        // positive class and add the true positive focal term.
        const float xp = cls[((size_t)b * N + n) * C + code];
        const float x = fminf(fmaxf(xp, F_EPS), 1.0f - F_EPS);
        const float om = 1.0f - x;
        delta = F_ALPHA * om * om * (-__logf(x))
              - (1.0f - F_ALPHA) * x * x * (-__logf(om));
    }

    np = waveReduceSum(np);
    rl = waveReduceSum(rl);
    if (lane == 0) { swsum[0][wave] = np; swsum[1][wave] = rl; }
    __syncthreads(); // publishes slim + swsum

    // ---------------- phase 2: negative-formula sweep (limit-fused) ----------
    // acc += x^2 * log2(1-x), x = fmin(v, lim); scaled once by -K_NEG.
    const float4* __restrict__ cp =
        reinterpret_cast<const float4*>(cls) + ((size_t)b * N + n0) * (C / 4);
    float a0 = 0.0f, a1 = 0.0f, a2 = 0.0f, a3 = 0.0f;
    #pragma unroll 4
    for (int k = 0; k < APB * C / 4 / 256; ++k) {   // 20 iterations
        const int f = k * 256 + tid;
        const int nl = f / 20;                      // magic-mul div
        const float lim = slim[nl];
        const float4 v = cp[f];
        const float vv[4] = {v.x, v.y, v.z, v.w};
        float* accp[4] = {&a0, &a1, &a2, &a3};
        #pragma unroll
        for (int q = 0; q < 4; ++q) {
            const float x = fminf(vv[q], lim);      // v >= 0; lim=0 kills term
            *accp[q] = fmaf(x * x, __log2f(1.0f - x), *accp[q]);
        }
    }
    const float cl_t = fmaf(-K_NEG, (a0 + a1) + (a2 + a3), delta);
    float cl = waveReduceSum(cl_t);
    if (lane == 0) swsum[2][wave] = cl;
    __syncthreads();

    if (tid == 0) {
        float4 r;
        r.x = swsum[0][0] + swsum[0][1] + swsum[0][2] + swsum[0][3];
        r.y = swsum[1][0] + swsum[1][1] + swsum[1][2] + swsum[1][3];
        r.z = swsum[2][0] + swsum[2][1] + swsum[2][2] + swsum[2][3];
        r.w = 0.0f;
        partials[b * BPI + blockIdx.x] = r;
    }
}

// One wave per image reduces its 256 block-partials, then thread 0 means.
__global__ __launch_bounds__(512) void final_kernel(
    const float4* __restrict__ partials, float* __restrict__ out)
{
    const int wave = threadIdx.x >> 6, lane = threadIdx.x & 63;
    __shared__ float simg[8];

    float np = 0.0f, rl = 0.0f, cl = 0.0f;
    for (int k = lane; k < BPI; k += 64) {
        const float4 p = partials[wave * BPI + k];
        np += p.x; rl += p.y; cl += p.z;
    }
    np = waveReduceSum(np);
    rl = waveReduceSum(rl);
    cl = waveReduceSum(cl);
    if (lane == 0) {
        const float c = cl / fmaxf(np, 1.0f);
        const float r = (np > 0.0f) ? rl / (fmaxf(np, 1.0f) * 4.0f) : 0.0f;
        simg[wave] = c + r;
    }
    __syncthreads();
    if (threadIdx.x == 0) {
        float t = 0.0f;
        #pragma unroll
        for (int b2 = 0; b2 < B; ++b2) t += simg[b2];
        out[0] = t * (1.0f / (float)B);
    }
}

extern "C" void kernel_launch(void* const* d_in, const int* in_sizes, int n_in,
                              void* d_out, int out_size, void* d_ws, size_t ws_size,
                              hipStream_t stream) {
    const float* classifications = (const float*)d_in[0]; // [B,N,C]
    const float* regressions     = (const float*)d_in[1]; // [B,N,4]
    const float* anchors         = (const float*)d_in[2]; // [1,N,4]
    const float* annotations     = (const float*)d_in[3]; // [B,M,5]
    float* out = (float*)d_out;
    float4* partials = (float4*)d_ws;                     // B*BPI = 2048 float4

    dim3 g(BPI, B);
    fused_kernel<<<g, 256, 0, stream>>>(anchors, regressions, annotations,
                                        classifications, partials);
    final_kernel<<<1, 512, 0, stream>>>(partials, out);
}